// Round 2
// baseline (650.360 us; speedup 1.0000x reference)
//
#include <hip/hip_runtime.h>
#include <hip/hip_bf16.h>

typedef unsigned short u16;
typedef unsigned int   u32;
typedef __attribute__((ext_vector_type(8))) short short8;
typedef __attribute__((ext_vector_type(4))) float f32x4;

#define B_   2
#define L_   2048
#define CDIM 384
#define DI   768
#define DXZ  1536
#define DTR  24
#define DS   16
#define NDBC 56
#define NC   64
#define TC   32
#define TL   32
#define EPSV 1e-5f

// converted-weight arena element offsets (bf16)
#define OFFW_WIN  0
#define OFFW_WXP  589824
#define OFFW_WOUT 632832
#define TOTW      927744

#define NBLK 256
#define NTHR 512

__device__ __forceinline__ float bf2f(u16 u) {
    union { u32 i; float f; } v; v.i = ((u32)u) << 16; return v.f;
}
__device__ __forceinline__ u16 f2bf(float f) {
    union { float f; u32 i; } v; v.f = f;
    u32 x = v.i;
    u32 r = (x + 0x7FFFu + ((x >> 16) & 1u)) >> 16;
    return (u16)r;
}

// device-scope grid barrier: grid=256 blocks <= 256 CUs at <=64KB LDS -> all
// blocks co-resident, no deadlock. Counters zeroed by memset before launch;
// each slot used exactly once per launch (monotonic arrive, no sense reversal).
__device__ __forceinline__ void gbar(int* bar, int slot) {
    __syncthreads();
    if (threadIdx.x == 0) {
        int* p = bar + slot * 64;                  // 256B per slot, own cacheline
        __threadfence();                           // release: flush producer caches
        __hip_atomic_fetch_add(p, 1, __ATOMIC_RELEASE, __HIP_MEMORY_SCOPE_AGENT);
        while (__hip_atomic_load(p, __ATOMIC_ACQUIRE, __HIP_MEMORY_SCOPE_AGENT) < NBLK)
            __builtin_amdgcn_s_sleep(8);
        __threadfence();                           // acquire: invalidate consumer caches
    }
    __syncthreads();
}

// LDS arena (64KB exactly), unioned across phases
struct P0S { float tile[CDIM][TL + 1]; float red[16][TL]; float red2[16][TL]; float mu[TL]; float rs[TL]; };
struct P3S { float sm[4][16][66]; };
struct P7S { float sm[4][64][64]; };
struct P8S { float tile[CDIM][TL + 1]; float mu[TL]; float rs[TL]; };

__global__ __launch_bounds__(NTHR, 2) void mega(
    const float* x, const float* ln1w, const float* ln1b,
    const float* ln2w, const float* ln2b,
    const float* win, const float* cw, const float* cb,
    const float* wxp, const float* wdt, const float* bdt,
    const float* alog, const float* Dw, const float* wout,
    u16* wbf, u16* xn, u16* xz, u16* ubf,
    float* dbc, float* chA, float* chB, float* hin,
    u16* ym, float* om, float* out, int* bar)
{
    __shared__ __align__(16) char smem[65536];
    int tid = threadIdx.x, blk = blockIdx.x;

    // ================= P0: LN1 (blocks 0..127) + weight convert (128..255) =================
    if (blk < 128) {
        P0S& S = *(P0S*)smem;
        int b = blk >> 6, l0 = (blk & 63) * TL;
        int cg = tid >> 5, li = tid & 31;
        const float* xp = x + (size_t)b * CDIM * L_ + l0 + li;
        float s = 0.f, s2 = 0.f;
#pragma unroll
        for (int c = cg; c < CDIM; c += 16) {           // coalesced along l
            float v = xp[(size_t)c * L_];
            S.tile[c][li] = v;
            s += v; s2 += v * v;
        }
        S.red[cg][li] = s; S.red2[cg][li] = s2;
        __syncthreads();
        if (tid < TL) {
            float ts = 0.f, ts2 = 0.f;
#pragma unroll
            for (int g = 0; g < 16; g++) { ts += S.red[g][tid]; ts2 += S.red2[g][tid]; }
            float mu = ts / CDIM;
            float var = ts2 / CDIM - mu * mu;
            S.mu[tid] = mu; S.rs[tid] = rsqrtf(var + EPSV);
        }
        __syncthreads();
        int wv = tid >> 6, lane = tid & 63;
#pragma unroll
        for (int r = 0; r < 4; r++) {
            int l = wv * 4 + r;
            float mu = S.mu[l], rs = S.rs[l];
            u16* op = xn + (size_t)(b * L_ + l0 + l) * CDIM;
#pragma unroll
            for (int j = 0; j < 6; j++) {
                int c = lane + 64 * j;
                float t = (S.tile[c][l] - mu) * rs * ln1w[c] + ln1b[c];
                op[c] = f2bf(t);                        // coalesced along c
            }
        }
    } else {
        int base = (blk - 128) * NTHR + tid;
        for (int e = base; e < TOTW; e += 128 * NTHR) {
            float v;
            if (e < OFFW_WXP)       v = win[e];
            else if (e < OFFW_WOUT) v = wxp[e - OFFW_WXP];
            else                    v = wout[e - OFFW_WOUT];
            wbf[e] = f2bf(v);
        }
    }
    gbar(bar, 0);

    // ================= P1: in_proj GEMM, 128x256 tile per block (2x4 waves of 64x64) =========
    if (blk < 192) {
        int wave = tid >> 6, lane = tid & 63;
        int wm = wave & 1, wn = wave >> 1;              // wn 0..3
        int bx = blk & 31, by = blk >> 5;               // 32 x 6 tiles
        int m0 = (bx * 2 + wm) * 64;
        int n0 = (by * 4 + wn) * 64;
        int r = lane & 15, q = lane >> 4;
        const u16* Bw = wbf + OFFW_WIN;
        f32x4 acc[4][4];
#pragma unroll
        for (int i = 0; i < 4; i++)
#pragma unroll
            for (int j = 0; j < 4; j++)
#pragma unroll
                for (int g = 0; g < 4; g++) acc[i][j][g] = 0.f;
#pragma unroll
        for (int k0 = 0; k0 < CDIM; k0 += 32) {
            short8 af[4], bfv[4];
            int ka = k0 + q * 8;
#pragma unroll
            for (int i = 0; i < 4; i++) {
                af[i]  = *(const short8*)(xn + (size_t)(m0 + i * 16 + r) * CDIM + ka);
                bfv[i] = *(const short8*)(Bw + (size_t)(n0 + i * 16 + r) * CDIM + ka);
            }
#pragma unroll
            for (int i = 0; i < 4; i++)
#pragma unroll
                for (int j = 0; j < 4; j++)
                    acc[i][j] = __builtin_amdgcn_mfma_f32_16x16x32_bf16(af[i], bfv[j], acc[i][j], 0, 0, 0);
        }
#pragma unroll
        for (int i = 0; i < 4; i++)
#pragma unroll
            for (int j = 0; j < 4; j++) {
                int col = n0 + j * 16 + r;
#pragma unroll
                for (int g = 0; g < 4; g++)
                    xz[(size_t)(m0 + i * 16 + q * 4 + g) * DXZ + col] = f2bf(acc[i][j][g]);
            }
    }
    gbar(bar, 1);

    // ================= P2: depthwise conv(4) + bias + SiLU =================
    {
#pragma unroll
        for (int it = 0; it < 2; it++) {
            int g = it * (NBLK * NTHR) + blk * NTHR + tid;
            if (g < 768 * 256) {
                int d = g % DI;
                int m0 = (g / DI) * 16;
                int l0 = m0 & (L_ - 1);
                float4 c4 = ((const float4*)cw)[d];
                float bias = cb[d];
                float w0, w1, w2;
                if (l0 == 0) { w0 = w1 = w2 = 0.f; }
                else {
                    w0 = bf2f(xz[(size_t)(m0 - 3) * DXZ + d]);
                    w1 = bf2f(xz[(size_t)(m0 - 2) * DXZ + d]);
                    w2 = bf2f(xz[(size_t)(m0 - 1) * DXZ + d]);
                }
#pragma unroll
                for (int i = 0; i < 16; i++) {
                    int m = m0 + i;
                    float cur = bf2f(xz[(size_t)m * DXZ + d]);
                    float acc = bias + w0 * c4.x + w1 * c4.y + w2 * c4.z + cur * c4.w;
                    float sg = 1.f / (1.f + __expf(-acc));
                    ubf[(size_t)m * DI + d] = f2bf(acc * sg);
                    w0 = w1; w1 = w2; w2 = cur;
                }
            }
        }
    }
    gbar(bar, 2);

    // ================= P3: x_proj GEMM, 16-row tile per block, 8-way split K ==========
    {
        P3S& S = *(P3S*)smem;
        int wave = tid >> 6, lane = tid & 63;
        int m0 = blk * 16;                               // 256 blocks x 16 = 4096 rows
        int r = lane & 15, q = lane >> 4;
        const u16* Bw = wbf + OFFW_WXP;
        f32x4 acc[4];
#pragma unroll
        for (int j = 0; j < 4; j++)
#pragma unroll
            for (int g = 0; g < 4; g++) acc[j][g] = 0.f;
        short8 zf;
#pragma unroll
        for (int e = 0; e < 8; e++) zf[e] = 0;
        int kb = wave * 96;                              // K=768 = 8 x 96
#pragma unroll
        for (int k0 = 0; k0 < 96; k0 += 32) {
            int ka = kb + k0 + q * 8;
            short8 af = *(const short8*)(ubf + (size_t)(m0 + r) * DI + ka);
            short8 bfv[4];
#pragma unroll
            for (int j = 0; j < 4; j++) {
                int n = j * 16 + r;
                bfv[j] = (n < NDBC) ? *(const short8*)(Bw + (size_t)n * DI + ka) : zf;
            }
#pragma unroll
            for (int j = 0; j < 4; j++)
                acc[j] = __builtin_amdgcn_mfma_f32_16x16x32_bf16(af, bfv[j], acc[j], 0, 0, 0);
        }
        if (wave < 4) {
#pragma unroll
            for (int j = 0; j < 4; j++)
#pragma unroll
                for (int g = 0; g < 4; g++)
                    S.sm[wave][q * 4 + g][j * 16 + r] = acc[j][g];
        }
        __syncthreads();
        if (wave >= 4) {
#pragma unroll
            for (int j = 0; j < 4; j++)
#pragma unroll
                for (int g = 0; g < 4; g++)
                    S.sm[wave - 4][q * 4 + g][j * 16 + r] += acc[j][g];
        }
        __syncthreads();
        for (int e = tid; e < 16 * 64; e += NTHR) {
            int row = e >> 6, col = e & 63;
            if (col < NDBC)
                dbc[(size_t)(m0 + row) * NDBC + col] =
                    S.sm[0][row][col] + S.sm[1][row][col] + S.sm[2][row][col] + S.sm[3][row][col];
        }
    }
    gbar(bar, 3);

    // ================= P4: scan pass 1 (chunk-local affine coefficients) ==========
    {
        int g = blk * NTHR + tid;
        if (g < 128 * DI) {
            int d = g % DI, bc = g / DI;
            int b = bc >> 6, chunk = bc & 63;
            float a[DS], ap[DS], bv[DS], wdtv[DTR];
#pragma unroll
            for (int s = 0; s < DS; s++) { a[s] = -__expf(alog[d * DS + s]); ap[s] = 1.f; bv[s] = 0.f; }
#pragma unroll
            for (int k = 0; k < DTR; k++) wdtv[k] = wdt[d * DTR + k];
            float bd = bdt[d];
            int t0 = b * L_ + chunk * TC;
#pragma unroll 2
            for (int t = t0; t < t0 + TC; t++) {
                const float* row = dbc + (size_t)t * NDBC;
                float acc = bd;
#pragma unroll
                for (int k = 0; k < DTR; k++) acc += row[k] * wdtv[k];
                float dd = (acc > 20.f) ? acc : __logf(1.f + __expf(acc));
                float du = dd * bf2f(ubf[(size_t)t * DI + d]);
#pragma unroll
                for (int s = 0; s < DS; s++) {
                    float dA = __expf(dd * a[s]);
                    bv[s] = dA * bv[s] + du * row[DTR + s];
                    ap[s] *= dA;
                }
            }
            float* pa = chA + (size_t)bc * DS * DI + d;
            float* pb = chB + (size_t)bc * DS * DI + d;
#pragma unroll
            for (int s = 0; s < DS; s++) { pa[(size_t)s * DI] = ap[s]; pb[(size_t)s * DI] = bv[s]; }
        }
    }
    gbar(bar, 4);

    // ================= P5: scan mid (64-chunk chain per (b,slot)) ==========
    {
        int idx = blk * NTHR + tid;
        if (idx < B_ * DI * DS) {
            int b = idx / (DI * DS);
            int rem = idx - b * (DI * DS);
            float h = 0.f;
#pragma unroll 4
            for (int c = 0; c < NC; c++) {
                size_t off = ((size_t)(b * NC + c) * DI) * DS + rem;
                hin[off] = h;
                h = chA[off] * h + chB[off];
            }
        }
    }
    gbar(bar, 5);

    // ================= P6: scan pass 2 (replay + u*D + silu(z) gate) ==========
    {
        int g = blk * NTHR + tid;
        if (g < 128 * DI) {
            int d = g % DI, bc = g / DI;
            int b = bc >> 6, chunk = bc & 63;
            float a[DS], h[DS], wdtv[DTR];
#pragma unroll
            for (int s = 0; s < DS; s++) a[s] = -__expf(alog[d * DS + s]);
#pragma unroll
            for (int k = 0; k < DTR; k++) wdtv[k] = wdt[d * DTR + k];
            float bd = bdt[d];
            const float* hp = hin + (size_t)bc * DS * DI + d;
#pragma unroll
            for (int s = 0; s < DS; s++) h[s] = hp[(size_t)s * DI];
            float dD = Dw[d];
            int t0 = b * L_ + chunk * TC;
#pragma unroll 2
            for (int t = t0; t < t0 + TC; t++) {
                const float* row = dbc + (size_t)t * NDBC;
                float acc = bd;
#pragma unroll
                for (int k = 0; k < DTR; k++) acc += row[k] * wdtv[k];
                float dd = (acc > 20.f) ? acc : __logf(1.f + __expf(acc));
                float uu = bf2f(ubf[(size_t)t * DI + d]);
                float du = dd * uu;
                float y = 0.f;
#pragma unroll
                for (int s = 0; s < DS; s++) {
                    float dA = __expf(dd * a[s]);
                    h[s] = dA * h[s] + du * row[DTR + s];
                    y += h[s] * row[DTR + DS + s];
                }
                float z = bf2f(xz[(size_t)t * DXZ + DI + d]);
                float sg = 1.f / (1.f + __expf(-z));
                ym[(size_t)t * DI + d] = f2bf((y + uu * dD) * (z * sg));
            }
        }
    }
    gbar(bar, 6);

    // ================= P7: out_proj GEMM, 64x64 tile, 8-way split K ==========
    {
        P7S& S = *(P7S*)smem;
        int wave = tid >> 6, lane = tid & 63;
        int r = lane & 15, q = lane >> 4;
        const u16* Bw = wbf + OFFW_WOUT;
        for (int t = blk; t < 384; t += NBLK) {          // 64 x 6 tiles
            int m0 = (t & 63) * 64, n0 = (t >> 6) * 64;
            f32x4 acc[4][4];
#pragma unroll
            for (int i = 0; i < 4; i++)
#pragma unroll
                for (int j = 0; j < 4; j++)
#pragma unroll
                    for (int g = 0; g < 4; g++) acc[i][j][g] = 0.f;
            int kb = wave * 96;                          // K=768 = 8 x 96
#pragma unroll
            for (int k0 = 0; k0 < 96; k0 += 32) {
                short8 af[4], bfv[4];
                int ka = kb + k0 + q * 8;
#pragma unroll
                for (int i = 0; i < 4; i++) {
                    af[i]  = *(const short8*)(ym + (size_t)(m0 + i * 16 + r) * DI + ka);
                    bfv[i] = *(const short8*)(Bw + (size_t)(n0 + i * 16 + r) * DI + ka);
                }
#pragma unroll
                for (int i = 0; i < 4; i++)
#pragma unroll
                    for (int j = 0; j < 4; j++)
                        acc[i][j] = __builtin_amdgcn_mfma_f32_16x16x32_bf16(af[i], bfv[j], acc[i][j], 0, 0, 0);
            }
            if (wave < 4) {
#pragma unroll
                for (int i = 0; i < 4; i++)
#pragma unroll
                    for (int j = 0; j < 4; j++)
#pragma unroll
                        for (int g = 0; g < 4; g++)
                            S.sm[wave][i * 16 + q * 4 + g][j * 16 + r] = acc[i][j][g];
            }
            __syncthreads();
            if (wave >= 4) {
#pragma unroll
                for (int i = 0; i < 4; i++)
#pragma unroll
                    for (int j = 0; j < 4; j++)
#pragma unroll
                        for (int g = 0; g < 4; g++)
                            S.sm[wave - 4][i * 16 + q * 4 + g][j * 16 + r] += acc[i][j][g];
            }
            __syncthreads();
            for (int e = tid; e < 64 * 64; e += NTHR) {
                int row = e >> 6, col = e & 63;
                om[(size_t)(m0 + row) * CDIM + n0 + col] =
                    S.sm[0][row][col] + S.sm[1][row][col] + S.sm[2][row][col] + S.sm[3][row][col];
            }
            __syncthreads();                             // protect smem before next tile
        }
    }
    gbar(bar, 7);

    // ================= P8: LN2 over (x + om), c-major fp32 out ==========
    if (blk < 128) {
        P8S& S = *(P8S*)smem;
        int b = blk >> 6, l0 = (blk & 63) * TL;
        int cg = tid >> 5, li = tid & 31;
        const float* xp = x + (size_t)b * CDIM * L_ + l0 + li;
#pragma unroll
        for (int c = cg; c < CDIM; c += 16) S.tile[c][li] = xp[(size_t)c * L_];
        __syncthreads();
        int wv = tid >> 6, lane = tid & 63;
#pragma unroll
        for (int r = 0; r < 4; r++) {
            int l = wv * 4 + r;
            const float* op = om + (size_t)(b * L_ + l0 + l) * CDIM;
            float s = 0.f, s2 = 0.f;
#pragma unroll
            for (int j = 0; j < 6; j++) {
                int c = lane + 64 * j;
                float t = S.tile[c][l] + op[c];
                S.tile[c][l] = t;
                s += t; s2 += t * t;
            }
#pragma unroll
            for (int off = 32; off > 0; off >>= 1) { s += __shfl_xor(s, off); s2 += __shfl_xor(s2, off); }
            if (lane == 0) {
                float mu = s / CDIM;
                float var = s2 / CDIM - mu * mu;
                S.mu[l] = mu; S.rs[l] = rsqrtf(var + EPSV);
            }
        }
        __syncthreads();
        float* outp = out + (size_t)b * CDIM * L_ + l0 + li;
        float mu = S.mu[li], rs = S.rs[li];
#pragma unroll
        for (int c = cg; c < CDIM; c += 16) {
            float t = (S.tile[c][li] - mu) * rs * ln2w[c] + ln2b[c];
            outp[(size_t)c * L_] = t;
        }
    }
}

extern "C" void kernel_launch(void* const* d_in, const int* in_sizes, int n_in,
                              void* d_out, int out_size, void* d_ws, size_t ws_size,
                              hipStream_t stream) {
    const float* x    = (const float*)d_in[0];
    const float* ln1w = (const float*)d_in[1];
    const float* ln1b = (const float*)d_in[2];
    const float* ln2w = (const float*)d_in[3];
    const float* ln2b = (const float*)d_in[4];
    const float* win  = (const float*)d_in[5];   // (1536, 384)
    const float* cw   = (const float*)d_in[6];   // (768, 1, 4)
    const float* cb   = (const float*)d_in[7];   // (768,)
    const float* wxp  = (const float*)d_in[8];   // (56, 768)
    const float* wdt  = (const float*)d_in[9];   // (768, 24)
    const float* bdt  = (const float*)d_in[10];  // (768,)
    const float* alog = (const float*)d_in[11];  // (768, 16)
    const float* Dw   = (const float*)d_in[12];  // (768,)
    const float* wout = (const float*)d_in[13];  // (384, 768)

    char* ws = (char*)d_ws;
    u16*   wbf  = (u16*)(ws + 0);              // 927744 bf16
    u16*   xn   = (u16*)(ws + 1855488);        // 4096*384 bf16
    u16*   xz   = (u16*)(ws + 5001216);        // 4096*1536 bf16
    u16*   ubf  = (u16*)(ws + 17584128);       // 4096*768 bf16
    float* dbc  = (float*)(ws + 23875584);     // 4096*56 f32
    float* chA  = (float*)(ws + 24793088);     // 2*64*16*768 f32 (s-major)
    float* chB  = (float*)(ws + 31084544);
    float* hin  = (float*)(ws + 37376000);
    u16*   ym   = (u16*)(ws + 43667456);       // 4096*768 bf16
    float* om   = (float*)(ws + 49958912);     // 4096*384 f32
    int*   bar  = (int*)(ws + 56623104);       // 8 slots * 256B

    hipMemsetAsync(bar, 0, 4096, stream);
    mega<<<NBLK, NTHR, 0, stream>>>(x, ln1w, ln1b, ln2w, ln2b, win, cw, cb,
                                    wxp, wdt, bdt, alog, Dw, wout,
                                    wbf, xn, xz, ubf, dbc, chA, chB, hin,
                                    ym, om, (float*)d_out, bar);
}

// Round 3
// 351.403 us; speedup vs baseline: 1.8508x; 1.8508x over previous
//
#include <hip/hip_runtime.h>
#include <hip/hip_bf16.h>

typedef unsigned short u16;
typedef unsigned int   u32;
typedef __attribute__((ext_vector_type(8))) short short8;
typedef __attribute__((ext_vector_type(4))) float f32x4;

#define B_   2
#define L_   2048
#define CDIM 384
#define DI   768
#define DXZ  1536
#define DTR  24
#define DS   16
#define NDBC 56
#define NC   64
#define TC   32
#define TL   32
#define EPSV 1e-5f

// converted-weight arena element offsets (bf16)
#define OFFW_WIN  0
#define OFFW_WXP  589824
#define OFFW_WOUT 632832
#define TOTW      927744

#define NBLK 256
#define NTHR 512

__device__ __forceinline__ float bf2f(u16 u) {
    union { u32 i; float f; } v; v.i = ((u32)u) << 16; return v.f;
}
__device__ __forceinline__ u16 f2bf(float f) {
    union { float f; u32 i; } v; v.f = f;
    u32 x = v.i;
    u32 r = (x + 0x7FFFu + ((x >> 16) & 1u)) >> 16;
    return (u16)r;
}

// Grid barrier, arrive-counter + broadcast-flag design:
//  - arrivals: RELAXED fetch_add on count line (no acquire traffic on hot path)
//  - last arriver sets a SEPARATE flag line (polls never contend with the adds)
//  - spinners poll RELAXED (no per-poll cache invalidation), s_sleep(16) backoff
//  - exactly one release fence (before add) + one acquire fence (after flag seen)
// grid=256 blocks <= 256 CUs at 64KB LDS -> all co-resident, no deadlock.
// Counters zeroed by memset before launch; each slot used once per launch.
__device__ __forceinline__ void gbar(int* bar, int slot) {
    __syncthreads();
    if (threadIdx.x == 0) {
        int* cnt = bar + slot * 64;                 // own 256B region
        int* flg = bar + 512 + slot * 64;           // own 256B region, 2KB away
        __threadfence();                            // release: make phase writes visible
        int v = __hip_atomic_fetch_add(cnt, 1, __ATOMIC_RELAXED, __HIP_MEMORY_SCOPE_AGENT);
        if (v == NBLK - 1) {
            __hip_atomic_store(flg, 1, __ATOMIC_RELAXED, __HIP_MEMORY_SCOPE_AGENT);
        } else {
            while (__hip_atomic_load(flg, __ATOMIC_RELAXED, __HIP_MEMORY_SCOPE_AGENT) == 0)
                __builtin_amdgcn_s_sleep(16);
        }
        __threadfence();                            // acquire: discard stale cached data
    }
    __syncthreads();
}

// LDS arena (64KB exactly), unioned across phases
struct P0S { float tile[CDIM][TL + 1]; float red[16][TL]; float red2[16][TL]; float mu[TL]; float rs[TL]; };
struct P3S { float sm[4][16][66]; };
struct P7S { float sm[4][64][64]; };
struct P8S { float tile[CDIM][TL + 1]; float mu[TL]; float rs[TL]; };

__global__ __launch_bounds__(NTHR, 2) void mega(
    const float* x, const float* ln1w, const float* ln1b,
    const float* ln2w, const float* ln2b,
    const float* win, const float* cw, const float* cb,
    const float* wxp, const float* wdt, const float* bdt,
    const float* alog, const float* Dw, const float* wout,
    u16* wbf, u16* xn, u16* xz, u16* ubf,
    float* dbc, float* chA, float* chB, float* hin,
    u16* ym, float* om, float* out, int* bar)
{
    __shared__ __align__(16) char smem[65536];
    int tid = threadIdx.x, blk = blockIdx.x;

    // ================= P0: LN1 (blocks 0..127) + weight convert (128..255) =================
    if (blk < 128) {
        P0S& S = *(P0S*)smem;
        int b = blk >> 6, l0 = (blk & 63) * TL;
        int cg = tid >> 5, li = tid & 31;
        const float* xp = x + (size_t)b * CDIM * L_ + l0 + li;
        float s = 0.f, s2 = 0.f;
#pragma unroll
        for (int c = cg; c < CDIM; c += 16) {           // coalesced along l
            float v = xp[(size_t)c * L_];
            S.tile[c][li] = v;
            s += v; s2 += v * v;
        }
        S.red[cg][li] = s; S.red2[cg][li] = s2;
        __syncthreads();
        if (tid < TL) {
            float ts = 0.f, ts2 = 0.f;
#pragma unroll
            for (int g = 0; g < 16; g++) { ts += S.red[g][tid]; ts2 += S.red2[g][tid]; }
            float mu = ts / CDIM;
            float var = ts2 / CDIM - mu * mu;
            S.mu[tid] = mu; S.rs[tid] = rsqrtf(var + EPSV);
        }
        __syncthreads();
        int wv = tid >> 6, lane = tid & 63;
#pragma unroll
        for (int r = 0; r < 4; r++) {
            int l = wv * 4 + r;
            float mu = S.mu[l], rs = S.rs[l];
            u16* op = xn + (size_t)(b * L_ + l0 + l) * CDIM;
#pragma unroll
            for (int j = 0; j < 6; j++) {
                int c = lane + 64 * j;
                float t = (S.tile[c][l] - mu) * rs * ln1w[c] + ln1b[c];
                op[c] = f2bf(t);                        // coalesced along c
            }
        }
    } else {
        int base = (blk - 128) * NTHR + tid;
        for (int e = base; e < TOTW; e += 128 * NTHR) {
            float v;
            if (e < OFFW_WXP)       v = win[e];
            else if (e < OFFW_WOUT) v = wxp[e - OFFW_WXP];
            else                    v = wout[e - OFFW_WOUT];
            wbf[e] = f2bf(v);
        }
    }
    gbar(bar, 0);

    // ================= P1: in_proj GEMM, 128x256 tile per block (2x4 waves of 64x64) =========
    if (blk < 192) {
        int wave = tid >> 6, lane = tid & 63;
        int wm = wave & 1, wn = wave >> 1;              // wn 0..3
        int bx = blk & 31, by = blk >> 5;               // 32 x 6 tiles
        int m0 = (bx * 2 + wm) * 64;
        int n0 = (by * 4 + wn) * 64;
        int r = lane & 15, q = lane >> 4;
        const u16* Bw = wbf + OFFW_WIN;
        f32x4 acc[4][4];
#pragma unroll
        for (int i = 0; i < 4; i++)
#pragma unroll
            for (int j = 0; j < 4; j++)
#pragma unroll
                for (int g = 0; g < 4; g++) acc[i][j][g] = 0.f;
#pragma unroll
        for (int k0 = 0; k0 < CDIM; k0 += 32) {
            short8 af[4], bfv[4];
            int ka = k0 + q * 8;
#pragma unroll
            for (int i = 0; i < 4; i++) {
                af[i]  = *(const short8*)(xn + (size_t)(m0 + i * 16 + r) * CDIM + ka);
                bfv[i] = *(const short8*)(Bw + (size_t)(n0 + i * 16 + r) * CDIM + ka);
            }
#pragma unroll
            for (int i = 0; i < 4; i++)
#pragma unroll
                for (int j = 0; j < 4; j++)
                    acc[i][j] = __builtin_amdgcn_mfma_f32_16x16x32_bf16(af[i], bfv[j], acc[i][j], 0, 0, 0);
        }
#pragma unroll
        for (int i = 0; i < 4; i++)
#pragma unroll
            for (int j = 0; j < 4; j++) {
                int col = n0 + j * 16 + r;
#pragma unroll
                for (int g = 0; g < 4; g++)
                    xz[(size_t)(m0 + i * 16 + q * 4 + g) * DXZ + col] = f2bf(acc[i][j][g]);
            }
    }
    gbar(bar, 1);

    // ================= P2: depthwise conv(4) + bias + SiLU =================
    {
#pragma unroll
        for (int it = 0; it < 2; it++) {
            int g = it * (NBLK * NTHR) + blk * NTHR + tid;
            if (g < 768 * 256) {
                int d = g % DI;
                int m0 = (g / DI) * 16;
                int l0 = m0 & (L_ - 1);
                float4 c4 = ((const float4*)cw)[d];
                float bias = cb[d];
                float w0, w1, w2;
                if (l0 == 0) { w0 = w1 = w2 = 0.f; }
                else {
                    w0 = bf2f(xz[(size_t)(m0 - 3) * DXZ + d]);
                    w1 = bf2f(xz[(size_t)(m0 - 2) * DXZ + d]);
                    w2 = bf2f(xz[(size_t)(m0 - 1) * DXZ + d]);
                }
#pragma unroll
                for (int i = 0; i < 16; i++) {
                    int m = m0 + i;
                    float cur = bf2f(xz[(size_t)m * DXZ + d]);
                    float acc = bias + w0 * c4.x + w1 * c4.y + w2 * c4.z + cur * c4.w;
                    float sg = 1.f / (1.f + __expf(-acc));
                    ubf[(size_t)m * DI + d] = f2bf(acc * sg);
                    w0 = w1; w1 = w2; w2 = cur;
                }
            }
        }
    }
    gbar(bar, 2);

    // ================= P3: x_proj GEMM, 16-row tile per block, 8-way split K ==========
    {
        P3S& S = *(P3S*)smem;
        int wave = tid >> 6, lane = tid & 63;
        int m0 = blk * 16;                               // 256 blocks x 16 = 4096 rows
        int r = lane & 15, q = lane >> 4;
        const u16* Bw = wbf + OFFW_WXP;
        f32x4 acc[4];
#pragma unroll
        for (int j = 0; j < 4; j++)
#pragma unroll
            for (int g = 0; g < 4; g++) acc[j][g] = 0.f;
        short8 zf;
#pragma unroll
        for (int e = 0; e < 8; e++) zf[e] = 0;
        int kb = wave * 96;                              // K=768 = 8 x 96
#pragma unroll
        for (int k0 = 0; k0 < 96; k0 += 32) {
            int ka = kb + k0 + q * 8;
            short8 af = *(const short8*)(ubf + (size_t)(m0 + r) * DI + ka);
            short8 bfv[4];
#pragma unroll
            for (int j = 0; j < 4; j++) {
                int n = j * 16 + r;
                bfv[j] = (n < NDBC) ? *(const short8*)(Bw + (size_t)n * DI + ka) : zf;
            }
#pragma unroll
            for (int j = 0; j < 4; j++)
                acc[j] = __builtin_amdgcn_mfma_f32_16x16x32_bf16(af, bfv[j], acc[j], 0, 0, 0);
        }
        if (wave < 4) {
#pragma unroll
            for (int j = 0; j < 4; j++)
#pragma unroll
                for (int g = 0; g < 4; g++)
                    S.sm[wave][q * 4 + g][j * 16 + r] = acc[j][g];
        }
        __syncthreads();
        if (wave >= 4) {
#pragma unroll
            for (int j = 0; j < 4; j++)
#pragma unroll
                for (int g = 0; g < 4; g++)
                    S.sm[wave - 4][q * 4 + g][j * 16 + r] += acc[j][g];
        }
        __syncthreads();
        for (int e = tid; e < 16 * 64; e += NTHR) {
            int row = e >> 6, col = e & 63;
            if (col < NDBC)
                dbc[(size_t)(m0 + row) * NDBC + col] =
                    S.sm[0][row][col] + S.sm[1][row][col] + S.sm[2][row][col] + S.sm[3][row][col];
        }
    }
    gbar(bar, 3);

    // ================= P4: scan pass 1 (chunk-local affine coefficients) ==========
    {
        int g = blk * NTHR + tid;
        if (g < 128 * DI) {
            int d = g % DI, bc = g / DI;
            int b = bc >> 6, chunk = bc & 63;
            float a[DS], ap[DS], bv[DS], wdtv[DTR];
#pragma unroll
            for (int s = 0; s < DS; s++) { a[s] = -__expf(alog[d * DS + s]); ap[s] = 1.f; bv[s] = 0.f; }
#pragma unroll
            for (int k = 0; k < DTR; k++) wdtv[k] = wdt[d * DTR + k];
            float bd = bdt[d];
            int t0 = b * L_ + chunk * TC;
#pragma unroll 2
            for (int t = t0; t < t0 + TC; t++) {
                const float* row = dbc + (size_t)t * NDBC;
                float acc = bd;
#pragma unroll
                for (int k = 0; k < DTR; k++) acc += row[k] * wdtv[k];
                float dd = (acc > 20.f) ? acc : __logf(1.f + __expf(acc));
                float du = dd * bf2f(ubf[(size_t)t * DI + d]);
#pragma unroll
                for (int s = 0; s < DS; s++) {
                    float dA = __expf(dd * a[s]);
                    bv[s] = dA * bv[s] + du * row[DTR + s];
                    ap[s] *= dA;
                }
            }
            float* pa = chA + (size_t)bc * DS * DI + d;
            float* pb = chB + (size_t)bc * DS * DI + d;
#pragma unroll
            for (int s = 0; s < DS; s++) { pa[(size_t)s * DI] = ap[s]; pb[(size_t)s * DI] = bv[s]; }
        }
    }
    gbar(bar, 4);

    // ================= P5: scan mid (64-chunk chain per (b,slot)) ==========
    {
        int idx = blk * NTHR + tid;
        if (idx < B_ * DI * DS) {
            int b = idx / (DI * DS);
            int rem = idx - b * (DI * DS);
            float h = 0.f;
#pragma unroll 4
            for (int c = 0; c < NC; c++) {
                size_t off = ((size_t)(b * NC + c) * DI) * DS + rem;
                hin[off] = h;
                h = chA[off] * h + chB[off];
            }
        }
    }
    gbar(bar, 5);

    // ================= P6: scan pass 2 (replay + u*D + silu(z) gate) ==========
    {
        int g = blk * NTHR + tid;
        if (g < 128 * DI) {
            int d = g % DI, bc = g / DI;
            int b = bc >> 6, chunk = bc & 63;
            float a[DS], h[DS], wdtv[DTR];
#pragma unroll
            for (int s = 0; s < DS; s++) a[s] = -__expf(alog[d * DS + s]);
#pragma unroll
            for (int k = 0; k < DTR; k++) wdtv[k] = wdt[d * DTR + k];
            float bd = bdt[d];
            const float* hp = hin + (size_t)bc * DS * DI + d;
#pragma unroll
            for (int s = 0; s < DS; s++) h[s] = hp[(size_t)s * DI];
            float dD = Dw[d];
            int t0 = b * L_ + chunk * TC;
#pragma unroll 2
            for (int t = t0; t < t0 + TC; t++) {
                const float* row = dbc + (size_t)t * NDBC;
                float acc = bd;
#pragma unroll
                for (int k = 0; k < DTR; k++) acc += row[k] * wdtv[k];
                float dd = (acc > 20.f) ? acc : __logf(1.f + __expf(acc));
                float uu = bf2f(ubf[(size_t)t * DI + d]);
                float du = dd * uu;
                float y = 0.f;
#pragma unroll
                for (int s = 0; s < DS; s++) {
                    float dA = __expf(dd * a[s]);
                    h[s] = dA * h[s] + du * row[DTR + s];
                    y += h[s] * row[DTR + DS + s];
                }
                float z = bf2f(xz[(size_t)t * DXZ + DI + d]);
                float sg = 1.f / (1.f + __expf(-z));
                ym[(size_t)t * DI + d] = f2bf((y + uu * dD) * (z * sg));
            }
        }
    }
    gbar(bar, 6);

    // ================= P7: out_proj GEMM, 64x64 tile, 8-way split K ==========
    {
        P7S& S = *(P7S*)smem;
        int wave = tid >> 6, lane = tid & 63;
        int r = lane & 15, q = lane >> 4;
        const u16* Bw = wbf + OFFW_WOUT;
        for (int t = blk; t < 384; t += NBLK) {          // 64 x 6 tiles
            int m0 = (t & 63) * 64, n0 = (t >> 6) * 64;
            f32x4 acc[4][4];
#pragma unroll
            for (int i = 0; i < 4; i++)
#pragma unroll
                for (int j = 0; j < 4; j++)
#pragma unroll
                    for (int g = 0; g < 4; g++) acc[i][j][g] = 0.f;
            int kb = wave * 96;                          // K=768 = 8 x 96
#pragma unroll
            for (int k0 = 0; k0 < 96; k0 += 32) {
                short8 af[4], bfv[4];
                int ka = kb + k0 + q * 8;
#pragma unroll
                for (int i = 0; i < 4; i++) {
                    af[i]  = *(const short8*)(ym + (size_t)(m0 + i * 16 + r) * DI + ka);
                    bfv[i] = *(const short8*)(Bw + (size_t)(n0 + i * 16 + r) * DI + ka);
                }
#pragma unroll
                for (int i = 0; i < 4; i++)
#pragma unroll
                    for (int j = 0; j < 4; j++)
                        acc[i][j] = __builtin_amdgcn_mfma_f32_16x16x32_bf16(af[i], bfv[j], acc[i][j], 0, 0, 0);
            }
            if (wave < 4) {
#pragma unroll
                for (int i = 0; i < 4; i++)
#pragma unroll
                    for (int j = 0; j < 4; j++)
#pragma unroll
                        for (int g = 0; g < 4; g++)
                            S.sm[wave][i * 16 + q * 4 + g][j * 16 + r] = acc[i][j][g];
            }
            __syncthreads();
            if (wave >= 4) {
#pragma unroll
                for (int i = 0; i < 4; i++)
#pragma unroll
                    for (int j = 0; j < 4; j++)
#pragma unroll
                        for (int g = 0; g < 4; g++)
                            S.sm[wave - 4][i * 16 + q * 4 + g][j * 16 + r] += acc[i][j][g];
            }
            __syncthreads();
            for (int e = tid; e < 64 * 64; e += NTHR) {
                int row = e >> 6, col = e & 63;
                om[(size_t)(m0 + row) * CDIM + n0 + col] =
                    S.sm[0][row][col] + S.sm[1][row][col] + S.sm[2][row][col] + S.sm[3][row][col];
            }
            __syncthreads();                             // protect smem before next tile
        }
    }
    gbar(bar, 7);

    // ================= P8: LN2 over (x + om), c-major fp32 out ==========
    if (blk < 128) {
        P8S& S = *(P8S*)smem;
        int b = blk >> 6, l0 = (blk & 63) * TL;
        int cg = tid >> 5, li = tid & 31;
        const float* xp = x + (size_t)b * CDIM * L_ + l0 + li;
#pragma unroll
        for (int c = cg; c < CDIM; c += 16) S.tile[c][li] = xp[(size_t)c * L_];
        __syncthreads();
        int wv = tid >> 6, lane = tid & 63;
#pragma unroll
        for (int r = 0; r < 4; r++) {
            int l = wv * 4 + r;
            const float* op = om + (size_t)(b * L_ + l0 + l) * CDIM;
            float s = 0.f, s2 = 0.f;
#pragma unroll
            for (int j = 0; j < 6; j++) {
                int c = lane + 64 * j;
                float t = S.tile[c][l] + op[c];
                S.tile[c][l] = t;
                s += t; s2 += t * t;
            }
#pragma unroll
            for (int off = 32; off > 0; off >>= 1) { s += __shfl_xor(s, off); s2 += __shfl_xor(s2, off); }
            if (lane == 0) {
                float mu = s / CDIM;
                float var = s2 / CDIM - mu * mu;
                S.mu[l] = mu; S.rs[l] = rsqrtf(var + EPSV);
            }
        }
        __syncthreads();
        float* outp = out + (size_t)b * CDIM * L_ + l0 + li;
        float mu = S.mu[li], rs = S.rs[li];
#pragma unroll
        for (int c = cg; c < CDIM; c += 16) {
            float t = (S.tile[c][li] - mu) * rs * ln2w[c] + ln2b[c];
            outp[(size_t)c * L_] = t;
        }
    }
}

extern "C" void kernel_launch(void* const* d_in, const int* in_sizes, int n_in,
                              void* d_out, int out_size, void* d_ws, size_t ws_size,
                              hipStream_t stream) {
    const float* x    = (const float*)d_in[0];
    const float* ln1w = (const float*)d_in[1];
    const float* ln1b = (const float*)d_in[2];
    const float* ln2w = (const float*)d_in[3];
    const float* ln2b = (const float*)d_in[4];
    const float* win  = (const float*)d_in[5];   // (1536, 384)
    const float* cw   = (const float*)d_in[6];   // (768, 1, 4)
    const float* cb   = (const float*)d_in[7];   // (768,)
    const float* wxp  = (const float*)d_in[8];   // (56, 768)
    const float* wdt  = (const float*)d_in[9];   // (768, 24)
    const float* bdt  = (const float*)d_in[10];  // (768,)
    const float* alog = (const float*)d_in[11];  // (768, 16)
    const float* Dw   = (const float*)d_in[12];  // (768,)
    const float* wout = (const float*)d_in[13];  // (384, 768)

    char* ws = (char*)d_ws;
    u16*   wbf  = (u16*)(ws + 0);              // 927744 bf16
    u16*   xn   = (u16*)(ws + 1855488);        // 4096*384 bf16
    u16*   xz   = (u16*)(ws + 5001216);        // 4096*1536 bf16
    u16*   ubf  = (u16*)(ws + 17584128);       // 4096*768 bf16
    float* dbc  = (float*)(ws + 23875584);     // 4096*56 f32
    float* chA  = (float*)(ws + 24793088);     // 2*64*16*768 f32 (s-major)
    float* chB  = (float*)(ws + 31084544);
    float* hin  = (float*)(ws + 37376000);
    u16*   ym   = (u16*)(ws + 43667456);       // 4096*768 bf16
    float* om   = (float*)(ws + 49958912);     // 4096*384 f32
    int*   bar  = (int*)(ws + 56623104);       // 8 count slots + 8 flag slots

    hipMemsetAsync(bar, 0, 4096, stream);
    mega<<<NBLK, NTHR, 0, stream>>>(x, ln1w, ln1b, ln2w, ln2b, win, cw, cb,
                                    wxp, wdt, bdt, alog, Dw, wout,
                                    wbf, xn, xz, ubf, dbc, chA, chB, hin,
                                    ym, om, (float*)d_out, bar);
}

// Round 4
// 260.030 us; speedup vs baseline: 2.5011x; 1.3514x over previous
//
#include <hip/hip_runtime.h>
#include <hip/hip_bf16.h>

typedef unsigned short u16;
typedef unsigned int   u32;
typedef __attribute__((ext_vector_type(8))) short short8;
typedef __attribute__((ext_vector_type(4))) float f32x4;

#define B_   2
#define L_   2048
#define CDIM 384
#define DI   768
#define DXZ  1536
#define DTR  24
#define DS   16
#define NDBC 56
#define NC   64
#define TC   32
#define TL   32
#define EPSV 1e-5f

// converted-weight arena element offsets (bf16)
#define OFFW_WIN  0
#define OFFW_WXP  589824
#define OFFW_WOUT 632832
#define TOTW      927744

__device__ __forceinline__ float bf2f(u16 u) {
    union { u32 i; float f; } v; v.i = ((u32)u) << 16; return v.f;
}
__device__ __forceinline__ u16 f2bf(float f) {
    union { float f; u32 i; } v; v.f = f;
    u32 x = v.i;
    u32 r = (x + 0x7FFFu + ((x >> 16) & 1u)) >> 16;
    return (u16)r;
}

// ---- LN1 (blocks 0..127) + weight conversion (blocks 128..255), one dispatch ----
__global__ __launch_bounds__(256) void ln1_convert(const float* __restrict__ x,
                                                   const float* __restrict__ w,
                                                   const float* __restrict__ bb,
                                                   u16* __restrict__ xn,
                                                   const float* __restrict__ win,
                                                   const float* __restrict__ wxp,
                                                   const float* __restrict__ wout,
                                                   u16* __restrict__ wdst) {
    __shared__ float tile[CDIM][TL + 1];
    __shared__ float red_s[8][TL];
    __shared__ float red_s2[8][TL];
    __shared__ float mu_s[TL], rs_s[TL];
    int tid = threadIdx.x, blk = blockIdx.x;
    if (blk >= 128) {
        int base = (blk - 128) * 256 + tid;
        for (int e = base; e < TOTW; e += 128 * 256) {
            float v;
            if (e < OFFW_WXP)       v = win[e];
            else if (e < OFFW_WOUT) v = wxp[e - OFFW_WXP];
            else                    v = wout[e - OFFW_WOUT];
            wdst[e] = f2bf(v);
        }
        return;
    }
    int b = blk >> 6;
    int l0 = (blk & 63) * TL;
    int cg = tid >> 5, li = tid & 31;
    const float* xp = x + (size_t)b * CDIM * L_ + l0 + li;
    float s = 0.f, s2 = 0.f;
#pragma unroll
    for (int c = cg; c < CDIM; c += 8) {           // coalesced along l
        float v = xp[(size_t)c * L_];
        tile[c][li] = v;
        s += v; s2 += v * v;
    }
    red_s[cg][li] = s; red_s2[cg][li] = s2;
    __syncthreads();
    if (tid < TL) {
        float ts = 0.f, ts2 = 0.f;
#pragma unroll
        for (int g = 0; g < 8; g++) { ts += red_s[g][tid]; ts2 += red_s2[g][tid]; }
        float mu = ts / CDIM;
        float var = ts2 / CDIM - mu * mu;
        mu_s[tid] = mu; rs_s[tid] = rsqrtf(var + EPSV);
    }
    __syncthreads();
    int wv = tid >> 6, lane = tid & 63;
#pragma unroll
    for (int r = 0; r < 8; r++) {
        int l = wv * 8 + r;
        float mu = mu_s[l], rs = rs_s[l];
        u16* op = xn + (size_t)(b * L_ + l0 + l) * CDIM;
#pragma unroll
        for (int j = 0; j < 6; j++) {
            int c = lane + 64 * j;
            float t = (tile[c][l] - mu) * rs * w[c] + bb[c];
            op[c] = f2bf(t);                       // coalesced along c
        }
    }
}

// ---- in_proj GEMM: 128x128 block (2x2 waves of 64x64), K compile-time ----
template<int KN>
__global__ __launch_bounds__(256) void gemm_in(const u16* __restrict__ A,
                                               const u16* __restrict__ Bm,
                                               u16* __restrict__ Cp, int Nn) {
    int wave = threadIdx.x >> 6, lane = threadIdx.x & 63;
    int wm = wave & 1, wn = wave >> 1;
    int m0 = (blockIdx.x * 2 + wm) * 64;
    int n0 = (blockIdx.y * 2 + wn) * 64;
    int r = lane & 15, q = lane >> 4;
    f32x4 acc[4][4];
#pragma unroll
    for (int i = 0; i < 4; i++)
#pragma unroll
        for (int j = 0; j < 4; j++)
#pragma unroll
            for (int g = 0; g < 4; g++) acc[i][j][g] = 0.f;
#pragma unroll
    for (int k0 = 0; k0 < KN; k0 += 32) {
        short8 af[4], bf[4];
        int ka = k0 + q * 8;
#pragma unroll
        for (int i = 0; i < 4; i++) {
            af[i] = *(const short8*)(A + (size_t)(m0 + i * 16 + r) * KN + ka);
            bf[i] = *(const short8*)(Bm + (size_t)(n0 + i * 16 + r) * KN + ka);
        }
#pragma unroll
        for (int i = 0; i < 4; i++)
#pragma unroll
            for (int j = 0; j < 4; j++)
                acc[i][j] = __builtin_amdgcn_mfma_f32_16x16x32_bf16(af[i], bf[j], acc[i][j], 0, 0, 0);
    }
#pragma unroll
    for (int i = 0; i < 4; i++)
#pragma unroll
        for (int j = 0; j < 4; j++) {
            int col = n0 + j * 16 + r;
#pragma unroll
            for (int g = 0; g < 4; g++)
                Cp[(size_t)(m0 + i * 16 + q * 4 + g) * Nn + col] = f2bf(acc[i][j][g]);
        }
}

// ---- depthwise causal conv (width 4) + bias + SiLU, sliding window ----
__global__ __launch_bounds__(256) void conv_silu(const u16* __restrict__ xz,
                                                 const float* __restrict__ cw,
                                                 const float* __restrict__ cb,
                                                 u16* __restrict__ ubf) {
    int d = blockIdx.y * 256 + threadIdx.x;
    int m0 = blockIdx.x * 16;
    int l0 = m0 & (L_ - 1);
    float4 c4 = ((const float4*)cw)[d];
    float bias = cb[d];
    float w0, w1, w2;
    if (l0 == 0) { w0 = w1 = w2 = 0.f; }
    else {
        w0 = bf2f(xz[(size_t)(m0 - 3) * DXZ + d]);
        w1 = bf2f(xz[(size_t)(m0 - 2) * DXZ + d]);
        w2 = bf2f(xz[(size_t)(m0 - 1) * DXZ + d]);
    }
#pragma unroll
    for (int i = 0; i < 16; i++) {
        int m = m0 + i;
        float cur = bf2f(xz[(size_t)m * DXZ + d]);
        float acc = bias + w0 * c4.x + w1 * c4.y + w2 * c4.z + cur * c4.w;
        float sg = 1.f / (1.f + __expf(-acc));
        ubf[(size_t)m * DI + d] = f2bf(acc * sg);
        w0 = w1; w1 = w2; w2 = cur;
    }
}

// ---- FUSED x_proj GEMM + scan pass 1. block = (b,chunk), 768 threads ----
// phase a: dbc tile (32x56) via 6-way split-K MFMA + LDS reduce (also -> global)
// phase b: scan1 with dbc read from LDS (broadcast), chA/chB s-major out
__global__ __launch_bounds__(768) void xp_scan1(const u16* __restrict__ ubf,
                                                const u16* __restrict__ wxpb,
                                                const float* __restrict__ alogf,
                                                const float* __restrict__ wdtf,
                                                const float* __restrict__ bdtf,
                                                float* __restrict__ dbc,
                                                float* __restrict__ chA,
                                                float* __restrict__ chB) {
    __shared__ float smR[12][16][68];            // 52.2 KB partials
    __shared__ float dbcS[TC][NDBC + 1];         // 7.3 KB
    int tid = threadIdx.x;
    int bc = blockIdx.x;                         // b*NC + chunk
    int t0g = (bc >> 6) * L_ + (bc & 63) * TC;   // global t base
    {   // ---- phase a: GEMM ----
        int wave = tid >> 6, lane = tid & 63;
        int mi = wave & 1, ks = wave >> 1;       // ks = K-slice 0..5 (128 each)
        int r = lane & 15, q = lane >> 4;
        f32x4 acc[4];
#pragma unroll
        for (int j = 0; j < 4; j++)
#pragma unroll
            for (int g = 0; g < 4; g++) acc[j][g] = 0.f;
        short8 zf;
#pragma unroll
        for (int e = 0; e < 8; e++) zf[e] = 0;
        int kb = ks * 128;
#pragma unroll
        for (int k0 = 0; k0 < 128; k0 += 32) {
            int ka = kb + k0 + q * 8;
            short8 af = *(const short8*)(ubf + (size_t)(t0g + mi * 16 + r) * DI + ka);
            short8 bfv[4];
#pragma unroll
            for (int j = 0; j < 4; j++) {
                int n = j * 16 + r;
                bfv[j] = (n < NDBC) ? *(const short8*)(wxpb + (size_t)n * DI + ka) : zf;
            }
#pragma unroll
            for (int j = 0; j < 4; j++)
                acc[j] = __builtin_amdgcn_mfma_f32_16x16x32_bf16(af, bfv[j], acc[j], 0, 0, 0);
        }
#pragma unroll
        for (int j = 0; j < 4; j++)
#pragma unroll
            for (int g = 0; g < 4; g++)
                smR[wave][q * 4 + g][j * 16 + r] = acc[j][g];
    }
    __syncthreads();
    for (int e = tid; e < TC * NDBC; e += 768) {   // reduce 6 K-slices
        int row = e / NDBC, col = e - row * NDBC;
        int mi = row >> 4, rr = row & 15;
        float v = 0.f;
#pragma unroll
        for (int ks = 0; ks < 6; ks++) v += smR[ks * 2 + mi][rr][col];
        dbcS[row][col] = v;
        dbc[(size_t)(t0g + row) * NDBC + col] = v;   // pass 2 reads this
    }
    __syncthreads();
    {   // ---- phase b: scan1, thread = d ----
        int d = tid;
        float a[DS], ap[DS], bv[DS], wdtv[DTR];
#pragma unroll
        for (int s = 0; s < DS; s++) { a[s] = -__expf(alogf[d * DS + s]); ap[s] = 1.f; bv[s] = 0.f; }
#pragma unroll
        for (int k = 0; k < DTR; k++) wdtv[k] = wdtf[d * DTR + k];
        float bd = bdtf[d];
#pragma unroll 2
        for (int t = 0; t < TC; t++) {
            float acc = bd;
#pragma unroll
            for (int k = 0; k < DTR; k++) acc += dbcS[t][k] * wdtv[k];
            float dd = (acc > 20.f) ? acc : __logf(1.f + __expf(acc));
            float du = dd * bf2f(ubf[(size_t)(t0g + t) * DI + d]);
#pragma unroll
            for (int s = 0; s < DS; s++) {
                float dA = __expf(dd * a[s]);
                bv[s] = dA * bv[s] + du * dbcS[t][DTR + s];
                ap[s] *= dA;
            }
        }
        float* pa = chA + (size_t)bc * DS * DI + d;
        float* pb = chB + (size_t)bc * DS * DI + d;
#pragma unroll
        for (int s = 0; s < DS; s++) { pa[(size_t)s * DI] = ap[s]; pb[(size_t)s * DI] = bv[s]; }
    }
}

// -------- scan mid: per (b,slot) scalar chain over chunks, coalesced --------
__global__ __launch_bounds__(256) void scan_mid(const float* __restrict__ chA,
                                                const float* __restrict__ chB,
                                                float* __restrict__ hin) {
    int idx = blockIdx.x * 256 + threadIdx.x;
    int b = idx / (DI * DS);
    int rem = idx - b * (DI * DS);
    float h = 0.f;
#pragma unroll 4
    for (int c = 0; c < NC; c++) {
        size_t off = ((size_t)(b * NC + c) * DI) * DS + rem;
        hin[off] = h;
        h = chA[off] * h + chB[off];
    }
}

// ---- FUSED scan pass 2 + out_proj GEMM. block = (b,chunk), 768 threads ----
// phase a: replay scan with h_in, ym tile (32x768 bf16) -> LDS (XOR-swizzled)
// phase b: om tile (32x384) = ymS @ wout^T, A-frags from LDS, 2x6 wave tiles
__global__ __launch_bounds__(768) void scan2_outproj(const u16* __restrict__ ubf,
                                                     const float* __restrict__ dbc,
                                                     const float* __restrict__ alogf,
                                                     const float* __restrict__ wdtf,
                                                     const float* __restrict__ bdtf,
                                                     const float* __restrict__ hin,
                                                     const float* __restrict__ Dwf,
                                                     const u16* __restrict__ xz,
                                                     const u16* __restrict__ woutb,
                                                     float* __restrict__ om) {
    __shared__ float dbcS[TC][NDBC + 1];               // 7.3 KB
    __shared__ __align__(16) u16 ymS[TC * DI];         // 48 KB, XOR-swizzled
    int tid = threadIdx.x;
    int bc = blockIdx.x;
    int t0g = (bc >> 6) * L_ + (bc & 63) * TC;
    for (int e = tid; e < TC * NDBC; e += 768) {       // stage dbc tile
        int row = e / NDBC, col = e - row * NDBC;
        dbcS[row][col] = dbc[(size_t)(t0g + row) * NDBC + col];
    }
    __syncthreads();
    {   // ---- phase a: scan2, thread = d ----
        int d = tid;
        float a[DS], h[DS], wdtv[DTR];
#pragma unroll
        for (int s = 0; s < DS; s++) a[s] = -__expf(alogf[d * DS + s]);
#pragma unroll
        for (int k = 0; k < DTR; k++) wdtv[k] = wdtf[d * DTR + k];
        float bd = bdtf[d];
        const float* hp = hin + (size_t)bc * DS * DI + d;
#pragma unroll
        for (int s = 0; s < DS; s++) h[s] = hp[(size_t)s * DI];   // coalesced
        float dD = Dwf[d];
#pragma unroll 2
        for (int t = 0; t < TC; t++) {
            float acc = bd;
#pragma unroll
            for (int k = 0; k < DTR; k++) acc += dbcS[t][k] * wdtv[k];
            float dd = (acc > 20.f) ? acc : __logf(1.f + __expf(acc));
            float uu = bf2f(ubf[(size_t)(t0g + t) * DI + d]);
            float du = dd * uu;
            float y = 0.f;
#pragma unroll
            for (int s = 0; s < DS; s++) {
                float dA = __expf(dd * a[s]);
                h[s] = dA * h[s] + du * dbcS[t][DTR + s];
                y += h[s] * dbcS[t][DTR + DS + s];
            }
            float z = bf2f(xz[(size_t)(t0g + t) * DXZ + DI + d]);
            float sg = 1.f / (1.f + __expf(-z));
            // XOR swizzle: u16 index d ^ ((t&7)<<3)  (T2: spreads A-frag rows)
            ymS[t * DI + (d ^ ((t & 7) << 3))] = f2bf((y + uu * dD) * (z * sg));
        }
    }
    __syncthreads();
    {   // ---- phase b: out_proj GEMM from LDS ----
        int wave = tid >> 6, lane = tid & 63;
        int mi = wave & 1, ni = wave >> 1;             // 2 x 6 tiles of 16x64
        int r = lane & 15, q = lane >> 4;
        int n0 = ni * 64;
        f32x4 acc[4];
#pragma unroll
        for (int j = 0; j < 4; j++)
#pragma unroll
            for (int g = 0; g < 4; g++) acc[j][g] = 0.f;
        int tl = mi * 16 + r;                          // local t row of A-frag
        int xw = (tl & 7) << 3;
#pragma unroll
        for (int k0 = 0; k0 < DI; k0 += 32) {
            int ka = k0 + q * 8;
            short8 af = *(const short8*)(&ymS[tl * DI + (ka ^ xw)]);
            short8 bfv[4];
#pragma unroll
            for (int j = 0; j < 4; j++)
                bfv[j] = *(const short8*)(woutb + (size_t)(n0 + j * 16 + r) * DI + ka);
#pragma unroll
            for (int j = 0; j < 4; j++)
                acc[j] = __builtin_amdgcn_mfma_f32_16x16x32_bf16(af, bfv[j], acc[j], 0, 0, 0);
        }
#pragma unroll
        for (int j = 0; j < 4; j++) {
            int col = n0 + j * 16 + r;
#pragma unroll
            for (int g = 0; g < 4; g++)
                om[(size_t)(t0g + mi * 16 + q * 4 + g) * CDIM + col] = acc[j][g];
        }
    }
}

// ---- LayerNorm 2 over (x + om), LDS tile transpose, FP32 c-major store ----
__global__ __launch_bounds__(256) void ln2_out(const float* __restrict__ x,
                                               const float* __restrict__ om,
                                               const float* __restrict__ w,
                                               const float* __restrict__ bb,
                                               float* __restrict__ out) {
    __shared__ float tile[CDIM][TL + 1];
    __shared__ float mu_s[TL], rs_s[TL];
    int tid = threadIdx.x, blk = blockIdx.x;
    int b = blk >> 6;
    int l0 = (blk & 63) * TL;
    int cg = tid >> 5, li = tid & 31;
    const float* xp = x + (size_t)b * CDIM * L_ + l0 + li;
#pragma unroll
    for (int c = cg; c < CDIM; c += 8) tile[c][li] = xp[(size_t)c * L_];  // coalesced
    __syncthreads();
    int wv = tid >> 6, lane = tid & 63;
#pragma unroll
    for (int r = 0; r < 8; r++) {
        int l = wv * 8 + r;
        const float* op = om + (size_t)(b * L_ + l0 + l) * CDIM;
        float s = 0.f, s2 = 0.f;
#pragma unroll
        for (int j = 0; j < 6; j++) {
            int c = lane + 64 * j;
            float t = tile[c][l] + op[c];            // om coalesced
            tile[c][l] = t;
            s += t; s2 += t * t;
        }
#pragma unroll
        for (int off = 32; off > 0; off >>= 1) { s += __shfl_xor(s, off); s2 += __shfl_xor(s2, off); }
        if (lane == 0) {
            float mu = s / CDIM;
            float var = s2 / CDIM - mu * mu;
            mu_s[l] = mu; rs_s[l] = rsqrtf(var + EPSV);
        }
    }
    __syncthreads();
    float* outp = out + (size_t)b * CDIM * L_ + l0 + li;
    float mu = mu_s[li], rs = rs_s[li];
#pragma unroll
    for (int c = cg; c < CDIM; c += 8) {
        float t = (tile[c][li] - mu) * rs * w[c] + bb[c];
        outp[(size_t)c * L_] = t;                    // fp32 out, coalesced along l
    }
}

extern "C" void kernel_launch(void* const* d_in, const int* in_sizes, int n_in,
                              void* d_out, int out_size, void* d_ws, size_t ws_size,
                              hipStream_t stream) {
    const float* x    = (const float*)d_in[0];
    const float* ln1w = (const float*)d_in[1];
    const float* ln1b = (const float*)d_in[2];
    const float* ln2w = (const float*)d_in[3];
    const float* ln2b = (const float*)d_in[4];
    const float* win  = (const float*)d_in[5];   // (1536, 384)
    const float* cw   = (const float*)d_in[6];   // (768, 1, 4)
    const float* cb   = (const float*)d_in[7];   // (768,)
    const float* wxp  = (const float*)d_in[8];   // (56, 768)
    const float* wdt  = (const float*)d_in[9];   // (768, 24)
    const float* bdt  = (const float*)d_in[10];  // (768,)
    const float* alog = (const float*)d_in[11];  // (768, 16)
    const float* Dw   = (const float*)d_in[12];  // (768,)
    const float* wout = (const float*)d_in[13];  // (384, 768)

    char* ws = (char*)d_ws;
    u16*   wbf   = (u16*)(ws + 0);             // 927744 bf16
    u16*   win_b  = wbf + OFFW_WIN;
    u16*   wxp_b  = wbf + OFFW_WXP;
    u16*   wout_b = wbf + OFFW_WOUT;
    u16*   xn    = (u16*)(ws + 1855488);       // 4096*384 bf16
    u16*   xz    = (u16*)(ws + 5001216);       // 4096*1536 bf16
    u16*   ubf   = (u16*)(ws + 17584128);      // 4096*768 bf16
    float* dbc   = (float*)(ws + 23875584);    // 4096*56 f32
    float* chA   = (float*)(ws + 24793088);    // 2*64*16*768 f32 (s-major)
    float* chB   = (float*)(ws + 31084544);
    float* hin   = (float*)(ws + 37376000);
    float* om    = (float*)(ws + 49958912);    // 4096*384 f32

    ln1_convert<<<dim3(256), 256, 0, stream>>>(x, ln1w, ln1b, xn, win, wxp, wout, wbf);
    gemm_in<384><<<dim3(32, 12), 256, 0, stream>>>(xn, win_b, xz, DXZ);
    conv_silu<<<dim3(256, 3), 256, 0, stream>>>(xz, cw, cb, ubf);
    xp_scan1<<<dim3(128), 768, 0, stream>>>(ubf, wxp_b, alog, wdt, bdt, dbc, chA, chB);
    scan_mid<<<96, 256, 0, stream>>>(chA, chB, hin);
    scan2_outproj<<<dim3(128), 768, 0, stream>>>(ubf, dbc, alog, wdt, bdt, hin, Dw, xz, wout_b, om);
    ln2_out<<<dim3(128), 256, 0, stream>>>(x, om, ln2w, ln2b, (float*)d_out);
}

// Round 5
// 202.512 us; speedup vs baseline: 3.2115x; 1.2840x over previous
//
#include <hip/hip_runtime.h>
#include <hip/hip_bf16.h>

typedef unsigned short u16;
typedef unsigned int   u32;
typedef __attribute__((ext_vector_type(8))) short short8;
typedef __attribute__((ext_vector_type(4))) float f32x4;

#define B_   2
#define L_   2048
#define CDIM 384
#define DI   768
#define DXZ  1536
#define DTR  24
#define DS   16
#define NDBC 56
#define NC2  128          // chunks per batch (TC=16)
#define TC   16
#define TL   32
#define EPSV 1e-5f

// converted-weight arena element offsets (bf16)
#define OFFW_WIN  0
#define OFFW_WXP  589824
#define OFFW_WOUT 632832
#define TOTW      927744

__device__ __forceinline__ float bf2f(u16 u) {
    union { u32 i; float f; } v; v.i = ((u32)u) << 16; return v.f;
}
__device__ __forceinline__ u16 f2bf(float f) {
    union { float f; u32 i; } v; v.f = f;
    u32 x = v.i;
    u32 r = (x + 0x7FFFu + ((x >> 16) & 1u)) >> 16;
    return (u16)r;
}

// ---- LN1 (blocks 0..127) + weight conversion (blocks 128..255), one dispatch ----
__global__ __launch_bounds__(256) void ln1_convert(const float* __restrict__ x,
                                                   const float* __restrict__ w,
                                                   const float* __restrict__ bb,
                                                   u16* __restrict__ xn,
                                                   const float* __restrict__ win,
                                                   const float* __restrict__ wxp,
                                                   const float* __restrict__ wout,
                                                   u16* __restrict__ wdst) {
    __shared__ float tile[CDIM][TL + 1];
    __shared__ float red_s[8][TL];
    __shared__ float red_s2[8][TL];
    __shared__ float mu_s[TL], rs_s[TL];
    int tid = threadIdx.x, blk = blockIdx.x;
    if (blk >= 128) {
        int base = (blk - 128) * 256 + tid;
        for (int e = base; e < TOTW; e += 128 * 256) {
            float v;
            if (e < OFFW_WXP)       v = win[e];
            else if (e < OFFW_WOUT) v = wxp[e - OFFW_WXP];
            else                    v = wout[e - OFFW_WOUT];
            wdst[e] = f2bf(v);
        }
        return;
    }
    int b = blk >> 6;
    int l0 = (blk & 63) * TL;
    int cg = tid >> 5, li = tid & 31;
    const float* xp = x + (size_t)b * CDIM * L_ + l0 + li;
    float s = 0.f, s2 = 0.f;
#pragma unroll
    for (int c = cg; c < CDIM; c += 8) {           // coalesced along l
        float v = xp[(size_t)c * L_];
        tile[c][li] = v;
        s += v; s2 += v * v;
    }
    red_s[cg][li] = s; red_s2[cg][li] = s2;
    __syncthreads();
    if (tid < TL) {
        float ts = 0.f, ts2 = 0.f;
#pragma unroll
        for (int g = 0; g < 8; g++) { ts += red_s[g][tid]; ts2 += red_s2[g][tid]; }
        float mu = ts / CDIM;
        float var = ts2 / CDIM - mu * mu;
        mu_s[tid] = mu; rs_s[tid] = rsqrtf(var + EPSV);
    }
    __syncthreads();
    int wv = tid >> 6, lane = tid & 63;
#pragma unroll
    for (int r = 0; r < 8; r++) {
        int l = wv * 8 + r;
        float mu = mu_s[l], rs = rs_s[l];
        u16* op = xn + (size_t)(b * L_ + l0 + l) * CDIM;
#pragma unroll
        for (int j = 0; j < 6; j++) {
            int c = lane + 64 * j;
            float t = (tile[c][l] - mu) * rs * w[c] + bb[c];
            op[c] = f2bf(t);                       // coalesced along c
        }
    }
}

// ---- in_proj GEMM: 128x128 block (2x2 waves of 64x64), K compile-time ----
template<int KN>
__global__ __launch_bounds__(256) void gemm_in(const u16* __restrict__ A,
                                               const u16* __restrict__ Bm,
                                               u16* __restrict__ Cp, int Nn) {
    int wave = threadIdx.x >> 6, lane = threadIdx.x & 63;
    int wm = wave & 1, wn = wave >> 1;
    int m0 = (blockIdx.x * 2 + wm) * 64;
    int n0 = (blockIdx.y * 2 + wn) * 64;
    int r = lane & 15, q = lane >> 4;
    f32x4 acc[4][4];
#pragma unroll
    for (int i = 0; i < 4; i++)
#pragma unroll
        for (int j = 0; j < 4; j++)
#pragma unroll
            for (int g = 0; g < 4; g++) acc[i][j][g] = 0.f;
#pragma unroll
    for (int k0 = 0; k0 < KN; k0 += 32) {
        short8 af[4], bf[4];
        int ka = k0 + q * 8;
#pragma unroll
        for (int i = 0; i < 4; i++) {
            af[i] = *(const short8*)(A + (size_t)(m0 + i * 16 + r) * KN + ka);
            bf[i] = *(const short8*)(Bm + (size_t)(n0 + i * 16 + r) * KN + ka);
        }
#pragma unroll
        for (int i = 0; i < 4; i++)
#pragma unroll
            for (int j = 0; j < 4; j++)
                acc[i][j] = __builtin_amdgcn_mfma_f32_16x16x32_bf16(af[i], bf[j], acc[i][j], 0, 0, 0);
    }
#pragma unroll
    for (int i = 0; i < 4; i++)
#pragma unroll
        for (int j = 0; j < 4; j++) {
            int col = n0 + j * 16 + r;
#pragma unroll
            for (int g = 0; g < 4; g++)
                Cp[(size_t)(m0 + i * 16 + q * 4 + g) * Nn + col] = f2bf(acc[i][j][g]);
        }
}

// ==== FUSED conv+SiLU + x_proj GEMM + scan pass 1.  block=(b,chunk16), 768 thr ====
// conv: thread=d sliding window -> ur[16] f32 regs + uS LDS bf16 (XOR-swizzled)
// gemm: waves 0..5, 6-way split-K(128), A-frags from uS, out 16x56 -> dbcS+global
// scan1: thread=d, dbc broadcast from LDS, u from regs -> chA/chB (s-major)
__global__ __launch_bounds__(768) void convxp_scan1(const u16* __restrict__ xz,
                                                    const float* __restrict__ cw,
                                                    const float* __restrict__ cb,
                                                    const u16* __restrict__ wxpb,
                                                    const float* __restrict__ alogf,
                                                    const float* __restrict__ wdtf,
                                                    const float* __restrict__ bdtf,
                                                    float* __restrict__ dbc,
                                                    float* __restrict__ chA,
                                                    float* __restrict__ chB) {
    __shared__ __align__(16) u16 uS[TC * DI];     // 24576 B
    __shared__ float smR[6][TC][60];              // 23040 B
    __shared__ float dbcS[TC][60];                // 3840 B
    int tid = threadIdx.x;
    int bc = blockIdx.x;                          // b*128 + chunk
    int b = bc >> 7, chunk = bc & 127;
    int t0g = b * L_ + chunk * TC;
    float ur[TC];
    {   // ---- conv + SiLU, thread = d ----
        int d = tid;
        float4 c4 = ((const float4*)cw)[d];
        float bias = cb[d];
        float w0, w1, w2;
        if (chunk == 0) { w0 = w1 = w2 = 0.f; }
        else {
            w0 = bf2f(xz[(size_t)(t0g - 3) * DXZ + d]);
            w1 = bf2f(xz[(size_t)(t0g - 2) * DXZ + d]);
            w2 = bf2f(xz[(size_t)(t0g - 1) * DXZ + d]);
        }
#pragma unroll
        for (int t = 0; t < TC; t++) {
            float cur = bf2f(xz[(size_t)(t0g + t) * DXZ + d]);
            float acc = bias + w0 * c4.x + w1 * c4.y + w2 * c4.z + cur * c4.w;
            float sg = 1.f / (1.f + __expf(-acc));
            ur[t] = acc * sg;
            uS[t * DI + (d ^ ((t & 7) << 3))] = f2bf(ur[t]);
            w0 = w1; w1 = w2; w2 = cur;
        }
    }
    __syncthreads();
    {   // ---- x_proj GEMM: waves 0..5, K-slice 128 each ----
        int wave = tid >> 6, lane = tid & 63;
        int r = lane & 15, q = lane >> 4;
        if (wave < 6) {
            f32x4 acc[4];
#pragma unroll
            for (int j = 0; j < 4; j++)
#pragma unroll
                for (int g = 0; g < 4; g++) acc[j][g] = 0.f;
            short8 zf;
#pragma unroll
            for (int e = 0; e < 8; e++) zf[e] = 0;
            int kb = wave * 128;
#pragma unroll
            for (int k0 = 0; k0 < 128; k0 += 32) {
                int ka = kb + k0 + q * 8;
                short8 af = *(const short8*)(&uS[r * DI + (ka ^ ((r & 7) << 3))]);
                short8 bfv[4];
#pragma unroll
                for (int j = 0; j < 4; j++) {
                    int n = j * 16 + r;
                    bfv[j] = (n < NDBC) ? *(const short8*)(wxpb + (size_t)n * DI + ka) : zf;
                }
#pragma unroll
                for (int j = 0; j < 4; j++)
                    acc[j] = __builtin_amdgcn_mfma_f32_16x16x32_bf16(af, bfv[j], acc[j], 0, 0, 0);
            }
#pragma unroll
            for (int j = 0; j < 4; j++) {
                int col = j * 16 + r;
                if (col < NDBC) {
#pragma unroll
                    for (int g = 0; g < 4; g++)
                        smR[wave][q * 4 + g][col] = acc[j][g];
                }
            }
        }
    }
    __syncthreads();
    for (int e = tid; e < TC * NDBC; e += 768) {   // reduce 6 K-slices
        int row = e / NDBC, col = e - row * NDBC;
        float v = 0.f;
#pragma unroll
        for (int ks = 0; ks < 6; ks++) v += smR[ks][row][col];
        dbcS[row][col] = v;
        dbc[(size_t)(t0g + row) * NDBC + col] = v;   // pass 2 stages this
    }
    __syncthreads();
    {   // ---- scan pass 1, thread = d ----
        int d = tid;
        float a[DS], ap[DS], bv[DS], wdtv[DTR];
#pragma unroll
        for (int s = 0; s < DS; s++) { a[s] = -__expf(alogf[d * DS + s]); ap[s] = 1.f; bv[s] = 0.f; }
#pragma unroll
        for (int k = 0; k < DTR; k++) wdtv[k] = wdtf[d * DTR + k];
        float bd = bdtf[d];
#pragma unroll 2
        for (int t = 0; t < TC; t++) {
            float acc = bd;
#pragma unroll
            for (int k = 0; k < DTR; k++) acc += dbcS[t][k] * wdtv[k];
            float dd = (acc > 20.f) ? acc : __logf(1.f + __expf(acc));
            float du = dd * ur[t];
#pragma unroll
            for (int s = 0; s < DS; s++) {
                float dA = __expf(dd * a[s]);
                bv[s] = dA * bv[s] + du * dbcS[t][DTR + s];
                ap[s] *= dA;
            }
        }
        float* pa = chA + (size_t)bc * DS * DI + d;
        float* pb = chB + (size_t)bc * DS * DI + d;
#pragma unroll
        for (int s = 0; s < DS; s++) { pa[(size_t)s * DI] = ap[s]; pb[(size_t)s * DI] = bv[s]; }
    }
}

// -------- scan mid: per (b,slot) scalar chain over 128 chunks, coalesced --------
__global__ __launch_bounds__(256) void scan_mid(const float* __restrict__ chA,
                                                const float* __restrict__ chB,
                                                float* __restrict__ hin) {
    int idx = blockIdx.x * 256 + threadIdx.x;   // 0..24575
    int b = idx / (DI * DS);
    int rem = idx - b * (DI * DS);
    float h = 0.f;
#pragma unroll 8
    for (int c = 0; c < NC2; c++) {
        size_t off = ((size_t)(b * NC2 + c) * DI) * DS + rem;
        hin[off] = h;
        h = chA[off] * h + chB[off];
    }
}

// ==== FUSED conv-replay + scan pass 2 + out_proj GEMM + LN2.  block=(b,chunk16) ====
// scan: thread=d, u recomputed (bit-identical to pass1), ym tile -> LDS bf16 swz
// gemm: waves 0..5 (16x64 tiles, K=768) -> smO (full 16x384 om rows per block)
// ln2: x tile staged over dead ymS, row-reduce per l, c-major f32 store
__global__ __launch_bounds__(768) void scan2_out_ln2(const u16* __restrict__ xz,
                                                     const float* __restrict__ cw,
                                                     const float* __restrict__ cb,
                                                     const float* __restrict__ dbc,
                                                     const float* __restrict__ alogf,
                                                     const float* __restrict__ wdtf,
                                                     const float* __restrict__ bdtf,
                                                     const float* __restrict__ hin,
                                                     const float* __restrict__ Dwf,
                                                     const u16* __restrict__ woutb,
                                                     const float* __restrict__ x,
                                                     const float* __restrict__ w2,
                                                     const float* __restrict__ b2,
                                                     float* __restrict__ out) {
    __shared__ __align__(16) char uni[TC * 388 * 4];   // ymS (24576B) then xT (24832B)
    __shared__ float smO[TC][388];                     // 24832 B
    __shared__ float dbcS[TC][60];                     // 3840 B
    __shared__ float mu_s[TC], rs_s[TC];
    u16* ymS = (u16*)uni;
    float (*xT)[388] = (float(*)[388])uni;
    int tid = threadIdx.x;
    int bc = blockIdx.x;
    int b = bc >> 7, chunk = bc & 127;
    int t0g = b * L_ + chunk * TC;
    for (int e = tid; e < TC * NDBC; e += 768) {       // stage dbc tile
        int row = e / NDBC, col = e - row * NDBC;
        dbcS[row][col] = dbc[(size_t)(t0g + row) * NDBC + col];
    }
    float ur[TC];
    {   // ---- conv replay (bit-identical order to pass 1) ----
        int d = tid;
        float4 c4 = ((const float4*)cw)[d];
        float bias = cb[d];
        float w0, w1, w2c;
        if (chunk == 0) { w0 = w1 = w2c = 0.f; }
        else {
            w0  = bf2f(xz[(size_t)(t0g - 3) * DXZ + d]);
            w1  = bf2f(xz[(size_t)(t0g - 2) * DXZ + d]);
            w2c = bf2f(xz[(size_t)(t0g - 1) * DXZ + d]);
        }
#pragma unroll
        for (int t = 0; t < TC; t++) {
            float cur = bf2f(xz[(size_t)(t0g + t) * DXZ + d]);
            float acc = bias + w0 * c4.x + w1 * c4.y + w2c * c4.z + cur * c4.w;
            float sg = 1.f / (1.f + __expf(-acc));
            ur[t] = acc * sg;
            w0 = w1; w1 = w2c; w2c = cur;
        }
    }
    __syncthreads();
    {   // ---- scan pass 2, thread = d ----
        int d = tid;
        float a[DS], h[DS], wdtv[DTR];
#pragma unroll
        for (int s = 0; s < DS; s++) a[s] = -__expf(alogf[d * DS + s]);
#pragma unroll
        for (int k = 0; k < DTR; k++) wdtv[k] = wdtf[d * DTR + k];
        float bd = bdtf[d];
        const float* hp = hin + (size_t)bc * DS * DI + d;
#pragma unroll
        for (int s = 0; s < DS; s++) h[s] = hp[(size_t)s * DI];   // coalesced
        float dD = Dwf[d];
#pragma unroll 2
        for (int t = 0; t < TC; t++) {
            float acc = bd;
#pragma unroll
            for (int k = 0; k < DTR; k++) acc += dbcS[t][k] * wdtv[k];
            float dd = (acc > 20.f) ? acc : __logf(1.f + __expf(acc));
            float uu = ur[t];
            float du = dd * uu;
            float y = 0.f;
#pragma unroll
            for (int s = 0; s < DS; s++) {
                float dA = __expf(dd * a[s]);
                h[s] = dA * h[s] + du * dbcS[t][DTR + s];
                y += h[s] * dbcS[t][DTR + DS + s];
            }
            float z = bf2f(xz[(size_t)(t0g + t) * DXZ + DI + d]);
            float sg = 1.f / (1.f + __expf(-z));
            ymS[t * DI + (d ^ ((t & 7) << 3))] = f2bf((y + uu * dD) * (z * sg));
        }
    }
    __syncthreads();
    {   // ---- out_proj GEMM from LDS: waves 0..5, n-tile 64 each, K=768 ----
        int wave = tid >> 6, lane = tid & 63;
        int r = lane & 15, q = lane >> 4;
        if (wave < 6) {
            int n0 = wave * 64;
            f32x4 acc[4];
#pragma unroll
            for (int j = 0; j < 4; j++)
#pragma unroll
                for (int g = 0; g < 4; g++) acc[j][g] = 0.f;
            int xw = (r & 7) << 3;
#pragma unroll
            for (int k0 = 0; k0 < DI; k0 += 32) {
                int ka = k0 + q * 8;
                short8 af = *(const short8*)(&ymS[r * DI + (ka ^ xw)]);
                short8 bfv[4];
#pragma unroll
                for (int j = 0; j < 4; j++)
                    bfv[j] = *(const short8*)(woutb + (size_t)(n0 + j * 16 + r) * DI + ka);
#pragma unroll
                for (int j = 0; j < 4; j++)
                    acc[j] = __builtin_amdgcn_mfma_f32_16x16x32_bf16(af, bfv[j], acc[j], 0, 0, 0);
            }
#pragma unroll
            for (int j = 0; j < 4; j++) {
                int col = n0 + j * 16 + r;
#pragma unroll
                for (int g = 0; g < 4; g++)
                    smO[q * 4 + g][col] = acc[j][g];
            }
        }
    }
    __syncthreads();
    // ---- stage x tile over dead ymS; add into smO ----
#pragma unroll
    for (int ii = 0; ii < 8; ii++) {
        int e = tid + ii * 768;                        // 6144 = 384c x 16l
        int c = e >> 4, l = e & 15;
        float xv = x[(size_t)b * CDIM * L_ + (size_t)c * L_ + chunk * TC + l];
        float t = xv + smO[l][c];
        xT[l][c] = t;                                  // keep pre-LN value
    }
    __syncthreads();
    {   // ---- LN2 row reduce: wave per l-row ----
        int wave = tid >> 6, lane = tid & 63;
        for (int row = wave; row < TC; row += 12) {
            float s = 0.f, s2 = 0.f;
#pragma unroll
            for (int j = 0; j < 6; j++) {
                float t = xT[row][lane + 64 * j];
                s += t; s2 += t * t;
            }
#pragma unroll
            for (int off = 32; off > 0; off >>= 1) { s += __shfl_xor(s, off); s2 += __shfl_xor(s2, off); }
            if (lane == 0) {
                float mu = s / CDIM;
                float var = s2 / CDIM - mu * mu;
                mu_s[row] = mu; rs_s[row] = rsqrtf(var + EPSV);
            }
        }
    }
    __syncthreads();
#pragma unroll
    for (int ii = 0; ii < 8; ii++) {
        int e = tid + ii * 768;
        int c = e >> 4, l = e & 15;
        float t = (xT[l][c] - mu_s[l]) * rs_s[l] * w2[c] + b2[c];
        out[(size_t)b * CDIM * L_ + (size_t)c * L_ + chunk * TC + l] = t;
    }
}

extern "C" void kernel_launch(void* const* d_in, const int* in_sizes, int n_in,
                              void* d_out, int out_size, void* d_ws, size_t ws_size,
                              hipStream_t stream) {
    const float* x    = (const float*)d_in[0];
    const float* ln1w = (const float*)d_in[1];
    const float* ln1b = (const float*)d_in[2];
    const float* ln2w = (const float*)d_in[3];
    const float* ln2b = (const float*)d_in[4];
    const float* win  = (const float*)d_in[5];   // (1536, 384)
    const float* cw   = (const float*)d_in[6];   // (768, 1, 4)
    const float* cb   = (const float*)d_in[7];   // (768,)
    const float* wxp  = (const float*)d_in[8];   // (56, 768)
    const float* wdt  = (const float*)d_in[9];   // (768, 24)
    const float* bdt  = (const float*)d_in[10];  // (768,)
    const float* alog = (const float*)d_in[11];  // (768, 16)
    const float* Dw   = (const float*)d_in[12];  // (768,)
    const float* wout = (const float*)d_in[13];  // (384, 768)

    char* ws = (char*)d_ws;
    u16*   wbf    = (u16*)(ws + 0);            // 927744 bf16
    u16*   win_b  = wbf + OFFW_WIN;
    u16*   wxp_b  = wbf + OFFW_WXP;
    u16*   wout_b = wbf + OFFW_WOUT;
    u16*   xn     = (u16*)(ws + 1855488);      // 4096*384 bf16
    u16*   xz     = (u16*)(ws + 5001216);      // 4096*1536 bf16
    float* dbc    = (float*)(ws + 17584128);   // 4096*56 f32
    float* chA    = (float*)(ws + 18501632);   // 256*16*768 f32 (s-major per bc)
    float* chB    = (float*)(ws + 31084544);
    float* hin    = (float*)(ws + 43667456);

    ln1_convert<<<dim3(256), 256, 0, stream>>>(x, ln1w, ln1b, xn, win, wxp, wout, wbf);
    gemm_in<384><<<dim3(32, 12), 256, 0, stream>>>(xn, win_b, xz, DXZ);
    convxp_scan1<<<dim3(256), 768, 0, stream>>>(xz, cw, cb, wxp_b, alog, wdt, bdt, dbc, chA, chB);
    scan_mid<<<96, 256, 0, stream>>>(chA, chB, hin);
    scan2_out_ln2<<<dim3(256), 768, 0, stream>>>(xz, cw, cb, dbc, alog, wdt, bdt, hin, Dw,
                                                 wout_b, x, ln2w, ln2b, (float*)d_out);
}